// Round 16
// baseline (6965.971 us; speedup 1.0000x reference)
//
#include <hip/hip_runtime.h>
#include <math.h>

// KimiK2 MoE gate. Round 16: w read per-lane DIRECTLY from global (L1/L2,
// vmcnt pipe, 1-q-group register prefetch) -- no w staging, no swizzle, no
// w barriers. LDS carries only x broadcasts (gl16 dbuf, r11 layout) ->
// DS pipe 8 reads/q-group (was 12). Semantics bit-identical to r7/9/11.
// Output: [T*8 indices as float][T*8 weights].

#define HH 7168
#define EE 256
#define BMT 32
#define BK 32
#define NTH 256
#define NT (HH / BK)

typedef float v4f __attribute__((ext_vector_type(4)));

struct SMem {
    float logits[BMT][EE];    // 32 KB
    float xbuf[2][BMT * BK];  // 8 KB (2 x 4 KB x slices)
    float bias[EE];
};

__device__ __forceinline__ void gl16(const void* g, void* l) {
    __builtin_amdgcn_global_load_lds(
        (__attribute__((address_space(1))) const void*)g,
        (__attribute__((address_space(3))) void*)l, 16, 0, 0);
}

#define LOADWG(dst, kk) do {                                                 \
    dst[0] = *(const v4f*)(wb0 + (kk));                                      \
    dst[1] = *(const v4f*)(wb1 + (kk));                                      \
    dst[2] = *(const v4f*)(wb2 + (kk));                                      \
    dst[3] = *(const v4f*)(wb3 + (kk)); } while (0)

#define FMAB(wr, q) do { _Pragma("unroll")                                   \
    for (int t_ = 0; t_ < 8; ++t_) {                                         \
        v4f xv_ = *(const v4f*)(xl + t_ * BK + (q) * 4);  /* broadcast */    \
        _Pragma("unroll")                                                    \
        for (int c_ = 0; c_ < 4; ++c_) {                                     \
            const float xs_ = xv_[c_];                                       \
            acc[t_][0] = fmaf(xs_, wr[0][c_], acc[t_][0]);                   \
            acc[t_][1] = fmaf(xs_, wr[1][c_], acc[t_][1]);                   \
            acc[t_][2] = fmaf(xs_, wr[2][c_], acc[t_][2]);                   \
            acc[t_][3] = fmaf(xs_, wr[3][c_], acc[t_][3]); } } } while (0)

__global__ __launch_bounds__(NTH, 2)
void moe_gate(const float* __restrict__ x, const float* __restrict__ w,
              const float* __restrict__ bias, float* __restrict__ out, int T) {
    __shared__ SMem sm;
    const int tid = threadIdx.x;
    const int bm = blockIdx.x * BMT;
    sm.bias[tid] = bias[tid];
    const int lane = tid & 63;
    const int wv = __builtin_amdgcn_readfirstlane(tid >> 6);
    const int l3 = (lane >> 3) & 7, l7 = lane & 7;

    // w: per-lane rows lane, lane+64, lane+128, lane+192, direct from global
    const float* wb0 = w + (size_t)lane * HH;
    const float* wb1 = wb0 + (size_t)64 * HH;
    const float* wb2 = wb0 + (size_t)128 * HH;
    const float* wb3 = wb0 + (size_t)192 * HH;

    // x staging (r11-proven): wave wv stages its 8 tokens, 1 gl16/thread
    const float* xsrc = x + (size_t)(bm + wv * 8 + l3) * HH + (l7 << 2);
    float* const xdst0 = &sm.xbuf[0][wv * 8 * BK];
    float* const xdst1 = &sm.xbuf[1][wv * 8 * BK];

    float acc[8][4];
    #pragma unroll
    for (int t = 0; t < 8; ++t)
        #pragma unroll
        for (int j = 0; j < 4; ++j) acc[t][j] = 0.f;

    // prologue: stage x slice 0; prefetch w q=0
    gl16(xsrc, xdst0);
    v4f wA[4], wB[4];
    LOADWG(wA, 0);
    __syncthreads();

    for (int ts = 0; ts < NT; ++ts) {
        const int b = ts & 1;
        const int k0 = ts * BK;
        if (ts + 1 < NT)
            gl16(xsrc + k0 + BK, b ? xdst0 : xdst1);
        const float* xl = &sm.xbuf[b][wv * 8 * BK];

        LOADWG(wB, k0 +  4); FMAB(wA, 0);
        LOADWG(wA, k0 +  8); FMAB(wB, 1);
        LOADWG(wB, k0 + 12); FMAB(wA, 2);
        LOADWG(wA, k0 + 16); FMAB(wB, 3);
        LOADWG(wB, k0 + 20); FMAB(wA, 4);
        LOADWG(wA, k0 + 24); FMAB(wB, 5);
        LOADWG(wB, k0 + 28); FMAB(wA, 6);
        if (ts + 1 < NT) LOADWG(wA, k0 + 32);
        FMAB(wB, 7);
        __syncthreads();  // x stage landed; all waves done with x buffer
    }

    // dump logits
    #pragma unroll
    for (int t = 0; t < 8; ++t)
        #pragma unroll
        for (int j = 0; j < 4; ++j)
            sm.logits[wv * 8 + t][lane + 64 * j] = acc[t][j];
    __syncthreads();

    // ---- routing: round-7 verbatim (ties -> higher index) ----
    for (int tt = wv; tt < BMT; tt += 4) {
        const int gt = bm + tt;
        float4 lg = *(const float4*)&sm.logits[tt][lane * 4];
        float lgv[4] = {lg.x, lg.y, lg.z, lg.w};
        float s[4], sc[4], m[4];
        #pragma unroll
        for (int j = 0; j < 4; ++j) {
            float e = (float)exp(-(double)lgv[j]);
            float u = __fadd_rn(1.0f, e);
            s[j] = __fdiv_rn(1.0f, u);
            sc[j] = __fadd_rn(s[j], sm.bias[lane * 4 + j]);
        }
        float a1 = fmaxf(sc[0], sc[1]), a2 = fminf(sc[0], sc[1]);
        if (sc[2] > a1) { a2 = a1; a1 = sc[2]; } else a2 = fmaxf(a2, sc[2]);
        if (sc[3] > a1) { a2 = a1; a1 = sc[3]; } else a2 = fmaxf(a2, sc[3]);
        #pragma unroll
        for (int off = 1; off <= 4; off <<= 1) {
            float b1 = __shfl_xor(a1, off);
            float b2 = __shfl_xor(a2, off);
            float m1 = fmaxf(a1, b1);
            float m2 = fmaxf(fminf(a1, b1), (a1 >= b1) ? a2 : b2);
            a1 = m1; a2 = m2;
        }
        float gsc = __fadd_rn(a1, a2);
        float gsv[8];
        #pragma unroll
        for (int g = 0; g < 8; ++g) gsv[g] = __shfl(gsc, g * 8);
        int gm = lane >> 3;
        int rank = 0;
        #pragma unroll
        for (int hh = 0; hh < 8; ++hh)
            rank += (gsv[hh] > gsv[gm]) || (gsv[hh] == gsv[gm] && hh > gm);
        bool selg = rank < 4;
        #pragma unroll
        for (int j = 0; j < 4; ++j) m[j] = selg ? sc[j] : 0.0f;

        float selw = 0.f; int seli = 0;
        #pragma unroll
        for (int k = 0; k < 8; ++k) {
            float bv = m[0]; int bj = 0;
            #pragma unroll
            for (int j = 1; j < 4; ++j)
                if (m[j] >= bv) { bv = m[j]; bj = j; }
            float v = bv; int ii = lane * 4 + bj;
            #pragma unroll
            for (int off = 1; off < 64; off <<= 1) {
                float ov = __shfl_xor(v, off);
                int oi = __shfl_xor(ii, off);
                if (ov > v || (ov == v && oi > ii)) { v = ov; ii = oi; }
            }
            int oj = ii & 3, ol = ii >> 2;
            float cand = (oj == 0) ? s[0] : (oj == 1) ? s[1]
                       : (oj == 2) ? s[2] : s[3];
            float wgt = __shfl(cand, ol);
            if (lane == k) { seli = ii; selw = wgt; }
            if (lane == ol) {
                if (oj == 0) m[0] = -1e30f;
                else if (oj == 1) m[1] = -1e30f;
                else if (oj == 2) m[2] = -1e30f;
                else m[3] = -1e30f;
            }
        }
        float wk[8];
        #pragma unroll
        for (int k = 0; k < 8; ++k) wk[k] = __shfl(selw, k);
        float denom = __fadd_rn(
            __fadd_rn(__fadd_rn(wk[0], wk[1]), __fadd_rn(wk[2], wk[3])),
            __fadd_rn(__fadd_rn(wk[4], wk[5]), __fadd_rn(wk[6], wk[7])));
        denom = __fadd_rn(denom, 1e-20f);
        if (lane < 8) {
            out[(size_t)gt * 8 + lane] = (float)seli;
            out[(size_t)T * 8 + (size_t)gt * 8 + lane] =
                __fmul_rn(__fdiv_rn(selw, denom), 2.5f);
        }
    }
}

extern "C" void kernel_launch(void* const* d_in, const int* in_sizes, int n_in,
                              void* d_out, int out_size, void* d_ws, size_t ws_size,
                              hipStream_t stream) {
    const float* x    = (const float*)d_in[0];
    const float* w    = (const float*)d_in[1];
    const float* bias = (const float*)d_in[2];
    float* out = (float*)d_out;
    const int T = in_sizes[0] / HH; // 16384
    moe_gate<<<T / BMT, NTH, 0, stream>>>(x, w, bias, out, T);
}

// Round 17
// 883.236 us; speedup vs baseline: 7.8869x; 7.8869x over previous
//
#include <hip/hip_runtime.h>
#include <math.h>

// KimiK2 MoE gate. Round 17 = round 11 verbatim (best measured: 882 us).
// All-DS operand path + async global_load_lds staging (double-buffered),
// w XOR-swizzled via pre-swizzled global source. DS-issue-bound at ~96
// b128-reads per q-group per CU = 2.25x FMA floor; measured within 2.5%
// of that structural wall. Semantics bit-identical to round 7 (ties ->
// higher index = numpy reversed-argsort). Output: [T*8 idx][T*8 weights].

#define HH 7168
#define EE 256
#define BMT 32
#define BK 32
#define NTH 256

typedef float v4f __attribute__((ext_vector_type(4)));

struct SMem {
    union {
        float wbuf[2][EE * BK];     // 64 KB (2 x 32 KB w slices)
        float logits[BMT][EE];      // 32 KB
    } u;
    float xbuf[2][BMT * BK];        // 8 KB
    float bias[EE];
};

__device__ __forceinline__ void gl16(const void* g, void* l) {
    __builtin_amdgcn_global_load_lds(
        (__attribute__((address_space(1))) const void*)g,
        (__attribute__((address_space(3))) void*)l, 16, 0, 0);
}

__global__ __launch_bounds__(NTH, 2)
void moe_gate(const float* __restrict__ x, const float* __restrict__ w,
              const float* __restrict__ bias, float* __restrict__ out, int T) {
    __shared__ SMem sm;
    const int tid = threadIdx.x;
    const int bm = blockIdx.x * BMT;
    sm.bias[tid] = bias[tid];
    const int lane = tid & 63;
    const int wv = __builtin_amdgcn_readfirstlane(tid >> 6);
    const int l3 = lane >> 3, l7 = lane & 7;

    // staging geometry: wave wv stages w rows [wv*64, wv*64+64), its 8 x rows
    const int cch = l7 ^ l3;  // pre-swizzled source chunk (row&7 == l3)
    const float* wsrc = w + (size_t)(wv * 64 + l3) * HH + cch * 4;
    const float* xsrc = x + (size_t)(bm + wv * 8 + l3) * HH + l7 * 4;
    float* const wdst0 = &sm.u.wbuf[0][wv * 64 * BK];
    float* const wdst1 = &sm.u.wbuf[1][wv * 64 * BK];
    float* const xdst0 = &sm.xbuf[0][wv * 8 * BK];
    float* const xdst1 = &sm.xbuf[1][wv * 8 * BK];

    float acc[8][4];
    #pragma unroll
    for (int t = 0; t < 8; ++t)
        #pragma unroll
        for (int j = 0; j < 4; ++j) acc[t][j] = 0.f;

    // prologue: stage slice 0 into buffer 0
    #pragma unroll
    for (int p = 0; p < 8; ++p)
        gl16(wsrc + (size_t)p * 8 * HH, wdst0 + p * 8 * BK);
    gl16(xsrc, xdst0);
    __syncthreads();

    const int NT = HH / BK; // 224
    for (int ts = 0; ts < NT; ++ts) {
        const int b = ts & 1;
        // stage next slice into the other buffer (async, overlaps compute)
        if (ts + 1 < NT) {
            const int k1 = (ts + 1) * BK;
            float* wd = (b ? wdst0 : wdst1);
            float* xd = (b ? xdst0 : xdst1);
            #pragma unroll
            for (int p = 0; p < 8; ++p)
                gl16(wsrc + (size_t)p * 8 * HH + k1, wd + p * 8 * BK);
            gl16(xsrc + k1, xd);
        }
        // compute slice ts from buffer b (all reads are in-order DS)
        const float* wl = sm.u.wbuf[b];
        const float* xl = &sm.xbuf[b][wv * 8 * BK];
        #pragma unroll
        for (int q = 0; q < 8; ++q) {
            const int wq = ((q ^ l7) << 2);       // swizzled k-chunk
            v4f w0 = *(const v4f*)&wl[(lane      ) * BK + wq];
            v4f w1 = *(const v4f*)&wl[(lane +  64) * BK + wq];
            v4f w2 = *(const v4f*)&wl[(lane + 128) * BK + wq];
            v4f w3 = *(const v4f*)&wl[(lane + 192) * BK + wq];
            v4f xv[8];
            #pragma unroll
            for (int t = 0; t < 8; ++t)           // uniform -> LDS broadcast
                xv[t] = *(const v4f*)&xl[t * BK + q * 4];
            #pragma unroll
            for (int t = 0; t < 8; ++t) {
                #pragma unroll
                for (int c = 0; c < 4; ++c) {     // k ascends per (t,expert)
                    float xs = xv[t][c];
                    acc[t][0] = fmaf(xs, w0[c], acc[t][0]);
                    acc[t][1] = fmaf(xs, w1[c], acc[t][1]);
                    acc[t][2] = fmaf(xs, w2[c], acc[t][2]);
                    acc[t][3] = fmaf(xs, w3[c], acc[t][3]);
                }
            }
        }
        __syncthreads();  // drains vmcnt (stage landed) + all waves done
    }

    // dump logits (union with wbuf: all w reads complete)
    #pragma unroll
    for (int t = 0; t < 8; ++t)
        #pragma unroll
        for (int j = 0; j < 4; ++j)
            sm.u.logits[wv * 8 + t][lane + 64 * j] = acc[t][j];
    __syncthreads();

    // ---- routing: round-7 verbatim (ties -> higher index) ----
    for (int tt = wv; tt < BMT; tt += 4) {
        const int gt = bm + tt;
        float4 lg = *(const float4*)&sm.u.logits[tt][lane * 4];
        float lgv[4] = {lg.x, lg.y, lg.z, lg.w};
        float s[4], sc[4], m[4];
        #pragma unroll
        for (int j = 0; j < 4; ++j) {
            float e = (float)exp(-(double)lgv[j]);
            float u = __fadd_rn(1.0f, e);
            s[j] = __fdiv_rn(1.0f, u);
            sc[j] = __fadd_rn(s[j], sm.bias[lane * 4 + j]);
        }
        float a1 = fmaxf(sc[0], sc[1]), a2 = fminf(sc[0], sc[1]);
        if (sc[2] > a1) { a2 = a1; a1 = sc[2]; } else a2 = fmaxf(a2, sc[2]);
        if (sc[3] > a1) { a2 = a1; a1 = sc[3]; } else a2 = fmaxf(a2, sc[3]);
        #pragma unroll
        for (int off = 1; off <= 4; off <<= 1) {
            float b1 = __shfl_xor(a1, off);
            float b2 = __shfl_xor(a2, off);
            float m1 = fmaxf(a1, b1);
            float m2 = fmaxf(fminf(a1, b1), (a1 >= b1) ? a2 : b2);
            a1 = m1; a2 = m2;
        }
        float gsc = __fadd_rn(a1, a2);
        float gsv[8];
        #pragma unroll
        for (int g = 0; g < 8; ++g) gsv[g] = __shfl(gsc, g * 8);
        int gm = lane >> 3;
        int rank = 0;
        #pragma unroll
        for (int hh = 0; hh < 8; ++hh)
            rank += (gsv[hh] > gsv[gm]) || (gsv[hh] == gsv[gm] && hh > gm);
        bool selg = rank < 4;
        #pragma unroll
        for (int j = 0; j < 4; ++j) m[j] = selg ? sc[j] : 0.0f;

        float selw = 0.f; int seli = 0;
        #pragma unroll
        for (int k = 0; k < 8; ++k) {
            float bv = m[0]; int bj = 0;
            #pragma unroll
            for (int j = 1; j < 4; ++j)
                if (m[j] >= bv) { bv = m[j]; bj = j; }
            float v = bv; int ii = lane * 4 + bj;
            #pragma unroll
            for (int off = 1; off < 64; off <<= 1) {
                float ov = __shfl_xor(v, off);
                int oi = __shfl_xor(ii, off);
                if (ov > v || (ov == v && oi > ii)) { v = ov; ii = oi; }
            }
            int oj = ii & 3, ol = ii >> 2;
            float cand = (oj == 0) ? s[0] : (oj == 1) ? s[1]
                       : (oj == 2) ? s[2] : s[3];
            float wgt = __shfl(cand, ol);
            if (lane == k) { seli = ii; selw = wgt; }
            if (lane == ol) {
                if (oj == 0) m[0] = -1e30f;
                else if (oj == 1) m[1] = -1e30f;
                else if (oj == 2) m[2] = -1e30f;
                else m[3] = -1e30f;
            }
        }
        float wk[8];
        #pragma unroll
        for (int k = 0; k < 8; ++k) wk[k] = __shfl(selw, k);
        float denom = __fadd_rn(
            __fadd_rn(__fadd_rn(wk[0], wk[1]), __fadd_rn(wk[2], wk[3])),
            __fadd_rn(__fadd_rn(wk[4], wk[5]), __fadd_rn(wk[6], wk[7])));
        denom = __fadd_rn(denom, 1e-20f);
        if (lane < 8) {
            out[(size_t)gt * 8 + lane] = (float)seli;
            out[(size_t)T * 8 + (size_t)gt * 8 + lane] =
                __fmul_rn(__fdiv_rn(selw, denom), 2.5f);
        }
    }
}

extern "C" void kernel_launch(void* const* d_in, const int* in_sizes, int n_in,
                              void* d_out, int out_size, void* d_ws, size_t ws_size,
                              hipStream_t stream) {
    const float* x    = (const float*)d_in[0];
    const float* w    = (const float*)d_in[1];
    const float* bias = (const float*)d_in[2];
    float* out = (float*)d_out;
    const int T = in_sizes[0] / HH; // 16384
    moe_gate<<<T / BMT, NTH, 0, stream>>>(x, w, bias, out, T);
}